// Round 3
// baseline (177.509 us; speedup 1.0000x reference)
//
#include <hip/hip_runtime.h>

// Covariance: B=8, T=512, F=513, M=8, AVERAGE=True
constexpr int kB  = 8;
constexpr int kT  = 512;
constexpr int kF  = 513;
constexpr int kM  = 8;
constexpr int kNP = 36;        // M*(M+1)/2 pairs
constexpr int kC  = 2 * kNP;   // 72 floats per (b,t,f)
constexpr int kFT = 64;        // f-tile width (= wave)
constexpr int kNFT = 9;        // ceil(F/64)
constexpr int kNTC = 16;       // t-chunks
constexpr int kTC = kT / kNTC; // 32 t per chunk
constexpr int kLDP = kC + 1;   // LDS row pad
constexpr int kS4 = kF * kC / 4;  // float4s per (b,t) slice = 9234
constexpr int kFB = (kS4 + 255) / 256;  // 37 fr4-blocks per (b,t)

// Stage 1: block per (b, f-tile, t-chunk). Lane = f (coalesced reads).
// 4 waves cover t = t0+wave step 4, 8 iters each. Partials -> out t-slices 1..16.
__global__ __launch_bounds__(256) void cov_partial(const float* __restrict__ in,
                                                   float* __restrict__ out) {
  const int bx = blockIdx.x;
  const int b  = bx / (kNFT * kNTC);
  const int r  = bx - b * (kNFT * kNTC);
  const int ft = r / kNTC;
  const int tc = r - ft * kNTC;
  const int tid  = threadIdx.x;
  const int wave = tid >> 6;
  const int lane = tid & 63;
  const int f = ft * kFT + lane;

  float accR[kNP], accI[kNP];
#pragma unroll
  for (int p = 0; p < kNP; ++p) { accR[p] = 0.0f; accI[p] = 0.0f; }

  if (f < kF) {
    const int t0 = tc * kTC + wave;
    const float* base = in + ((size_t)(b * kT + t0) * kF + f) * (2 * kM);
    const size_t tstep = (size_t)4 * kF * (2 * kM);
#pragma unroll 2
    for (int it = 0; it < kTC / 4; ++it) {
      const float* ptr = base + it * tstep;
      const float4 r0 = *(const float4*)(ptr + 0);
      const float4 r1 = *(const float4*)(ptr + 4);
      const float4 i0 = *(const float4*)(ptr + 8);
      const float4 i1 = *(const float4*)(ptr + 12);
      const float re[kM] = {r0.x, r0.y, r0.z, r0.w, r1.x, r1.y, r1.z, r1.w};
      const float im[kM] = {i0.x, i0.y, i0.z, i0.w, i1.x, i1.y, i1.z, i1.w};
      int p = 0;
#pragma unroll
      for (int i = 0; i < kM; ++i) {
#pragma unroll
        for (int j = i; j < kM; ++j) {
          accR[p] += re[i] * re[j] + im[i] * im[j];
          accI[p] += re[i] * im[j] - im[i] * re[j];
          ++p;
        }
      }
    }
  }

  __shared__ float buf[2][kFT * kLDP];
  float* my = buf[wave & 1] + lane * kLDP;
  if (wave < 2) {
#pragma unroll
    for (int p = 0; p < kNP; ++p) { my[p] = accR[p]; my[kNP + p] = accI[p]; }
  }
  __syncthreads();
  if (wave >= 2) {
#pragma unroll
    for (int p = 0; p < kNP; ++p) { my[p] += accR[p]; my[kNP + p] += accI[p]; }
  }
  __syncthreads();

  const int nf = min(kFT, kF - ft * kFT);
  float* dst = out + ((size_t)(b * kT + (1 + tc)) * kF + ft * kFT) * kC;
  const int n = nf * kC;
  for (int e = tid; e < n; e += 256) {
    const int l = (unsigned)e / (unsigned)kC;
    const int p = e - l * kC;
    dst[e] = buf[0][l * kLDP + p] + buf[1][l * kLDP + p];
  }
}

// Stage 2: sum the 16 partial slices (t=1..16), scale, write t=0 slice.
// One thread per float4 of the mean slice.
__global__ __launch_bounds__(256) void cov_combine(float4* __restrict__ out) {
  const int total4 = kB * kS4;                    // 73,872
  const int idx = blockIdx.x * 256 + threadIdx.x;
  if (idx >= total4) return;
  const int b = (unsigned)idx / (unsigned)kS4;
  const int fr4 = idx - b * kS4;
  const size_t bbase = (size_t)b * kT * kS4;
  float4 s = make_float4(0.f, 0.f, 0.f, 0.f);
#pragma unroll
  for (int k = 0; k < kNTC; ++k) {
    const float4 v = out[bbase + (size_t)(1 + k) * kS4 + fr4];
    s.x += v.x; s.y += v.y; s.z += v.z; s.w += v.w;
  }
  const float sc = 1.0f / kT;
  s.x *= sc; s.y *= sc; s.z *= sc; s.w *= sc;
  out[bbase + fr4] = s;
}

// Stage 3: broadcast. Thread reads its mean float4 once, writes 8 t-slices.
// Block = (b, tc in [0,64), fb in [0,37)); lane covers contiguous fr4.
__global__ __launch_bounds__(256) void cov_bcast(float4* __restrict__ out) {
  const int bid = blockIdx.x;
  const int b   = bid / (64 * kFB);
  const int rem = bid - b * (64 * kFB);
  const int tc  = rem / kFB;
  const int fb  = rem - tc * kFB;
  const int fr4 = fb * 256 + threadIdx.x;
  if (fr4 >= kS4) return;
  const size_t bbase = (size_t)b * kT * kS4;
  const float4 v = out[bbase + fr4];           // mean at t=0 (L2-resident)
  float4* dst = out + bbase + (size_t)(tc * 8) * kS4 + fr4;
#pragma unroll
  for (int k = 0; k < 8; ++k) {
    *dst = v;                                  // t = tc*8+k; tc=0,k=0 is a
    dst += kS4;                                // value-identical self-copy
  }
}

extern "C" void kernel_launch(void* const* d_in, const int* in_sizes, int n_in,
                              void* d_out, int out_size, void* d_ws, size_t ws_size,
                              hipStream_t stream) {
  const float* in = (const float*)d_in[0];
  float* out = (float*)d_out;

  cov_partial<<<dim3(kB * kNFT * kNTC), dim3(256), 0, stream>>>(in, out);

  const int total4 = kB * kS4;
  cov_combine<<<dim3((total4 + 255) / 256), dim3(256), 0, stream>>>((float4*)out);

  cov_bcast<<<dim3(kB * 64 * kFB), dim3(256), 0, stream>>>((float4*)out);
}

// Round 4
// 152.221 us; speedup vs baseline: 1.1661x; 1.1661x over previous
//
#include <hip/hip_runtime.h>

// Covariance: B=8, T=512, F=513, M=8, AVERAGE=True
constexpr int kB  = 8;
constexpr int kT  = 512;
constexpr int kF  = 513;
constexpr int kM  = 8;
constexpr int kNP = 36;        // M*(M+1)/2 pairs
constexpr int kC  = 2 * kNP;   // 72 floats per (b,t,f)
constexpr int kFT = 64;        // f-tile width (= wave)
constexpr int kNFT = 9;        // ceil(F/64)
constexpr int kNTC = 16;       // t-chunks
constexpr int kTC = kT / kNTC; // 32 t per chunk (8 per wave)
constexpr int kLDP = kC + 1;   // LDS row pad
constexpr int kS4 = kF * kC / 4;  // float4s per (b,t) slice = 9234

// Stage 1: block per (b, f-tile, t-chunk). Lane = f (4KB contiguous per load).
// Wave w handles t in [tc*32 + w*8, +8), TWO t's per iteration so 8 float4
// loads are in flight (~8KB/CU outstanding -> covers HBM BW*latency product).
__global__ __launch_bounds__(256) void cov_partial(const float* __restrict__ in,
                                                   float* __restrict__ out) {
  const int bx = blockIdx.x;
  const int b  = bx / (kNFT * kNTC);
  const int r  = bx - b * (kNFT * kNTC);
  const int ft = r / kNTC;
  const int tc = r - ft * kNTC;
  const int tid  = threadIdx.x;
  const int wave = tid >> 6;
  const int lane = tid & 63;
  const int f = ft * kFT + lane;

  float accR[kNP], accI[kNP];
#pragma unroll
  for (int p = 0; p < kNP; ++p) { accR[p] = 0.0f; accI[p] = 0.0f; }

  if (f < kF) {
    const int t0 = tc * kTC + wave * 8;
    const float* base = in + ((size_t)(b * kT + t0) * kF + f) * (2 * kM);
    const size_t tstep = (size_t)kF * (2 * kM);   // one t
#pragma unroll
    for (int it = 0; it < 4; ++it) {
      const float* pa = base + (2 * it) * tstep;
      const float* pb = pa + tstep;
      // issue all 8 loads up front (independent addresses)
      const float4 ar0 = *(const float4*)(pa + 0);
      const float4 ar1 = *(const float4*)(pa + 4);
      const float4 ai0 = *(const float4*)(pa + 8);
      const float4 ai1 = *(const float4*)(pa + 12);
      const float4 br0 = *(const float4*)(pb + 0);
      const float4 br1 = *(const float4*)(pb + 4);
      const float4 bi0 = *(const float4*)(pb + 8);
      const float4 bi1 = *(const float4*)(pb + 12);
      {
        const float re[kM] = {ar0.x, ar0.y, ar0.z, ar0.w, ar1.x, ar1.y, ar1.z, ar1.w};
        const float im[kM] = {ai0.x, ai0.y, ai0.z, ai0.w, ai1.x, ai1.y, ai1.z, ai1.w};
        int p = 0;
#pragma unroll
        for (int i = 0; i < kM; ++i)
#pragma unroll
          for (int j = i; j < kM; ++j) {
            accR[p] += re[i] * re[j] + im[i] * im[j];
            accI[p] += re[i] * im[j] - im[i] * re[j];
            ++p;
          }
      }
      {
        const float re[kM] = {br0.x, br0.y, br0.z, br0.w, br1.x, br1.y, br1.z, br1.w};
        const float im[kM] = {bi0.x, bi0.y, bi0.z, bi0.w, bi1.x, bi1.y, bi1.z, bi1.w};
        int p = 0;
#pragma unroll
        for (int i = 0; i < kM; ++i)
#pragma unroll
          for (int j = i; j < kM; ++j) {
            accR[p] += re[i] * re[j] + im[i] * im[j];
            accI[p] += re[i] * im[j] - im[i] * re[j];
            ++p;
          }
      }
    }
  }

  // cross-wave combine via padded LDS (conflict-free), transpose to
  // f-major contiguous layout for coalesced partial-slice stores
  __shared__ float buf[2][kFT * kLDP];
  float* my = buf[wave & 1] + lane * kLDP;
  if (wave < 2) {
#pragma unroll
    for (int p = 0; p < kNP; ++p) { my[p] = accR[p]; my[kNP + p] = accI[p]; }
  }
  __syncthreads();
  if (wave >= 2) {
#pragma unroll
    for (int p = 0; p < kNP; ++p) { my[p] += accR[p]; my[kNP + p] += accI[p]; }
  }
  __syncthreads();

  const int nf = min(kFT, kF - ft * kFT);
  float* dst = out + ((size_t)(b * kT + (1 + tc)) * kF + ft * kFT) * kC;
  const int n = nf * kC;
  for (int e = tid; e < n; e += 256) {
    const int l = (unsigned)e / (unsigned)kC;
    const int p = e - l * kC;
    dst[e] = buf[0][l * kLDP + p] + buf[1][l * kLDP + p];
  }
}

// Stage 2: sum the 16 partial slices (t=1..16), scale, write t=0 slice.
__global__ __launch_bounds__(256) void cov_combine(float4* __restrict__ out) {
  const int total4 = kB * kS4;                    // 73,872
  const int idx = blockIdx.x * 256 + threadIdx.x;
  if (idx >= total4) return;
  const int b = (unsigned)idx / (unsigned)kS4;
  const int fr4 = idx - b * kS4;
  const size_t bbase = (size_t)b * kT * kS4;
  float4 s = make_float4(0.f, 0.f, 0.f, 0.f);
#pragma unroll
  for (int k = 0; k < kNTC; ++k) {
    const float4 v = out[bbase + (size_t)(1 + k) * kS4 + fr4];
    s.x += v.x; s.y += v.y; s.z += v.z; s.w += v.w;
  }
  const float sc = 1.0f / kT;
  s.x *= sc; s.y *= sc; s.z *= sc; s.w *= sc;
  out[bbase + fr4] = s;
}

// Stage 3: broadcast t=0 slice to all t. PURELY LINEAR write stream
// (one thread per output float4) — measured fastest pattern (R1 vs R2).
__global__ __launch_bounds__(256) void cov_bcast(float4* __restrict__ out) {
  const unsigned total4 = (unsigned)kB * kT * kF * (kC / 4);  // 37,822,464
  const unsigned idx = blockIdx.x * 256u + threadIdx.x;
  if (idx >= total4) return;
  const unsigned g = idx / (kC / 4);          // (b*T + t)*F + f
  const unsigned r = idx - g * (kC / 4);
  const unsigned b = g / (unsigned)(kT * kF);
  const unsigned f = g % (unsigned)kF;
  const unsigned src = (b * (unsigned)(kT * kF) + f) * (kC / 4) + r;
  out[idx] = out[src];   // t=0 is a value-identical self-copy
}

extern "C" void kernel_launch(void* const* d_in, const int* in_sizes, int n_in,
                              void* d_out, int out_size, void* d_ws, size_t ws_size,
                              hipStream_t stream) {
  const float* in = (const float*)d_in[0];
  float* out = (float*)d_out;

  cov_partial<<<dim3(kB * kNFT * kNTC), dim3(256), 0, stream>>>(in, out);

  const int total4 = kB * kS4;
  cov_combine<<<dim3((total4 + 255) / 256), dim3(256), 0, stream>>>((float4*)out);

  const unsigned total4b = (unsigned)kB * kT * kF * (kC / 4);
  cov_bcast<<<dim3((total4b + 255u) / 256u), dim3(256), 0, stream>>>((float4*)out);
}